// Round 4
// baseline (459.098 us; speedup 1.0000x reference)
//
#include <hip/hip_runtime.h>
#include <cstdint>

// ---------------------------------------------------------------------------
// GroupedQueryAttention: B=2 N=2048 DIM=2048 HQ=16 HKV=4 HD=128, causal, RoPE.
// f32 I/O, bf16 internals. Round 4: barrier-free attention — each wave owns
// 32 queries x 1 head; K/V MFMA fragments loaded straight from L2 (no LDS
// staging, no __syncthreads); P round-trips per-wave LDS only.
// ---------------------------------------------------------------------------

typedef __bf16 bf16_t;
typedef __attribute__((ext_vector_type(8))) __bf16 bf16x8;
typedef __attribute__((ext_vector_type(4))) float f32x4;

#define B_    2
#define N_    2048
#define DIM_  2048
#define HQ_   16
#define HKV_  4
#define HD_   128
#define KVD_  512
#define SCALE_ 0.08838834764831845f  // 128^-0.5

// ---------------------------------------------------------------------------
// cos/sin table: [2048][64] each, f32.  inv_freq = 10000^(-i/64) (base_adj==1)
// ---------------------------------------------------------------------------
__global__ void k_sincos(float* __restrict__ cosT, float* __restrict__ sinT) {
  int idx = blockIdx.x * 256 + threadIdx.x;  // 2048*64
  int i = idx & 63;
  int n = idx >> 6;
  float inv = expf(-(float)i * (9.210340371976184f / 64.0f));  // ln(1e4)/64
  float ang = (float)n * inv;
  cosT[idx] = cosf(ang);
  sinT[idx] = sinf(ang);
}

// ---------------------------------------------------------------------------
// C = A @ W^T + bias.  A:[M][K] (f32 if AF32 else bf16), W:[N][K] f32,
// C:[M][N] (f32 if CF32 else bf16).  Dual-issue via blockIdx.z.
// 128x128 tile, BK=64, 4 waves each 64x64. LDS bf16 [128][64], XOR swizzle.
// ---------------------------------------------------------------------------
template <bool AF32, bool CF32>
__global__ __launch_bounds__(256, 2) void k_gemm_bt(
    const void* __restrict__ A0v, const float* __restrict__ W0,
    const float* __restrict__ b0, void* __restrict__ C0v,
    const void* __restrict__ A1v, const float* __restrict__ W1,
    const float* __restrict__ b1, void* __restrict__ C1v,
    int M, int N, int K)
{
  const void* Av = A0v; const float* W = W0;
  const float* bias = b0; void* Cv = C0v;
  if (blockIdx.z == 1) { Av = A1v; W = W1; bias = b1; Cv = C1v; }

  __shared__ bf16_t As[128 * 64];
  __shared__ bf16_t Bs[128 * 64];
  const int tid  = threadIdx.x;
  const int lane = tid & 63;
  const int wave = tid >> 6;
  const int l15  = lane & 15;
  const int lg   = lane >> 4;
  const int bm = blockIdx.x, bn = blockIdx.y;
  const int wr = (wave >> 1) * 64, wc = (wave & 1) * 64;

  f32x4 acc[4][4] = {};

  uint8_t* AsB = (uint8_t*)As;
  uint8_t* BsB = (uint8_t*)Bs;

  for (int k0 = 0; k0 < K; k0 += 64) {
    // stage: 128 rows x 64 cols per tile = 1024 8-elem chunks, 256 thr x 4
    for (int i = 0; i < 4; ++i) {
      int c = i * 256 + tid;
      int row = c >> 3;            // 0..127
      int k8  = (c & 7) * 8;       // element offset within K-tile
      bf16x8 va, vb;
      if (AF32) {
        const float* ap = (const float*)Av + (size_t)(bm * 128 + row) * K + k0 + k8;
        f32x4 alo = *(const f32x4*)ap;
        f32x4 ahi = *(const f32x4*)(ap + 4);
        va[0] = (bf16_t)alo[0]; va[1] = (bf16_t)alo[1];
        va[2] = (bf16_t)alo[2]; va[3] = (bf16_t)alo[3];
        va[4] = (bf16_t)ahi[0]; va[5] = (bf16_t)ahi[1];
        va[6] = (bf16_t)ahi[2]; va[7] = (bf16_t)ahi[3];
      } else {
        va = *(const bf16x8*)((const bf16_t*)Av + (size_t)(bm * 128 + row) * K + k0 + k8);
      }
      {
        const float* wp = W + (size_t)(bn * 128 + row) * K + k0 + k8;
        f32x4 wlo = *(const f32x4*)wp;
        f32x4 whi = *(const f32x4*)(wp + 4);
        vb[0] = (bf16_t)wlo[0]; vb[1] = (bf16_t)wlo[1];
        vb[2] = (bf16_t)wlo[2]; vb[3] = (bf16_t)wlo[3];
        vb[4] = (bf16_t)whi[0]; vb[5] = (bf16_t)whi[1];
        vb[6] = (bf16_t)whi[2]; vb[7] = (bf16_t)whi[3];
      }
      int sw = (k8 * 2) ^ ((row & 7) << 4);
      *(bf16x8*)(AsB + row * 128 + sw) = va;
      *(bf16x8*)(BsB + row * 128 + sw) = vb;
    }
    __syncthreads();
    for (int kk = 0; kk < 2; ++kk) {
      const int koff = kk * 64 + (lg << 4);
      bf16x8 fa[4], fb[4];
      for (int fi = 0; fi < 4; ++fi) {
        int row = wr + fi * 16 + l15;
        fa[fi] = *(const bf16x8*)(AsB + row * 128 + (koff ^ ((row & 7) << 4)));
      }
      for (int fj = 0; fj < 4; ++fj) {
        int row = wc + fj * 16 + l15;
        fb[fj] = *(const bf16x8*)(BsB + row * 128 + (koff ^ ((row & 7) << 4)));
      }
      for (int fi = 0; fi < 4; ++fi)
        for (int fj = 0; fj < 4; ++fj)
          acc[fi][fj] = __builtin_amdgcn_mfma_f32_16x16x32_bf16(
              fa[fi], fb[fj], acc[fi][fj], 0, 0, 0);
    }
    __syncthreads();
  }

  // epilogue: C/D layout col=lane&15, row=(lane>>4)*4+r
  const int r0 = lg * 4;
  for (int fi = 0; fi < 4; ++fi) {
    for (int rr = 0; rr < 4; ++rr) {
      int grow = bm * 128 + wr + fi * 16 + r0 + rr;
      size_t rowoff = (size_t)grow * N;
      for (int fj = 0; fj < 4; ++fj) {
        int gcol = bn * 128 + wc + fj * 16 + l15;
        float v = acc[fi][fj][rr] + bias[gcol];
        if (CF32) ((float*)Cv)[rowoff + gcol] = v;
        else      ((bf16_t*)Cv)[rowoff + gcol] = (bf16_t)v;
      }
    }
  }
}

// ---------------------------------------------------------------------------
// RoPE in-place on X:[4096][nheads*128] bf16.  lgnh = log2(nheads). outScale
// folds the attention softmax scale into Q.
// ---------------------------------------------------------------------------
__global__ void k_rope(bf16_t* __restrict__ X, const float* __restrict__ cosT,
                       const float* __restrict__ sinT, int lgnh, float outScale)
{
  int idx = blockIdx.x * 256 + threadIdx.x;
  int d = idx & 63;
  int h = (idx >> 6) & ((1 << lgnh) - 1);
  int row = idx >> (6 + lgnh);
  int n = row & (N_ - 1);
  float c = cosT[(n << 6) + d];
  float s = sinT[(n << 6) + d];
  size_t base = (size_t)row * (size_t)(128 << lgnh) + (h << 7) + d;
  float x1 = (float)X[base];
  float x2 = (float)X[base + 64];
  X[base]      = (bf16_t)((x1 * c - x2 * s) * outScale);
  X[base + 64] = (bf16_t)((x2 * c + x1 * s) * outScale);
}

// ---------------------------------------------------------------------------
// Vp:[4096][512] -> Vt:[B*HKV][128][2048]  (Vt[bh][d][n] = Vp[b*2048+n][hkv*128+d])
// ---------------------------------------------------------------------------
__global__ void k_transpose_v(const bf16_t* __restrict__ Vp, bf16_t* __restrict__ Vt)
{
  __shared__ bf16_t tile[64][72];
  const int tid = threadIdx.x;
  const int r0 = blockIdx.x * 64;  // global row (b*2048+n)
  const int d0 = blockIdx.y * 64;  // col in [0,512)
  for (int r = 0; r < 2; ++r) {
    int n = r * 32 + (tid >> 3);
    int dc = (tid & 7) * 8;
    *(uint4*)&tile[n][dc] = *(const uint4*)(Vp + (size_t)(r0 + n) * KVD_ + d0 + dc);
  }
  __syncthreads();
  const int b = r0 >> 11;
  const int nseq = r0 & (N_ - 1);
  for (int r = 0; r < 2; ++r) {
    int dd = r * 32 + (tid >> 3);
    int nc = (tid & 7) * 8;
    int dglob = d0 + dd;
    int hkv = dglob >> 7, dloc = dglob & 127;
    union { bf16_t h[8]; uint4 v; } pk;
    for (int j = 0; j < 8; ++j) pk.h[j] = tile[nc + j][dd];
    size_t drow = (size_t)(b * HKV_ + hkv) * 128 + dloc;
    *(uint4*)(Vt + drow * N_ + nseq + nc) = pk.v;
  }
}

// ---------------------------------------------------------------------------
// Flash attention, causal GQA, barrier-free. Grid (16, B*HQ); 4 waves/block;
// each wave owns qtile = blockIdx.x*4+wave (32 queries) of head blockIdx.y.
// K and V^T fragments loaded directly from global (L2-resident); per-wave
// P round-trip through LDS (lgkmcnt-ordered, no barriers anywhere).
// ---------------------------------------------------------------------------
__global__ __launch_bounds__(256, 2) void k_attn(
    const bf16_t* __restrict__ Qp, const bf16_t* __restrict__ Kp,
    const bf16_t* __restrict__ Vt, bf16_t* __restrict__ AO)
{
  __shared__ bf16_t Ps[4][2][16 * 72];
  const int tid = threadIdx.x, lane = tid & 63, wave = tid >> 6;
  const int l15 = lane & 15, lg = lane >> 4;
  const int qtile = blockIdx.x * 4 + wave;   // 0..63 (32 queries each)
  const int bh = blockIdx.y;
  const int b = bh >> 4, hq = bh & 15, hkv = hq >> 2;

  // Q fragments: 2 row-frags x 4 k-steps (RoPE'd, scale folded)
  bf16x8 qf[2][4];
  for (int rf = 0; rf < 2; ++rf) {
    size_t qrow = (size_t)b * N_ + qtile * 32 + rf * 16 + l15;
    const uint8_t* qb = (const uint8_t*)Qp + (qrow * DIM_ + (size_t)hq * HD_) * 2 + lg * 16;
    for (int ks = 0; ks < 4; ++ks)
      qf[rf][ks] = *(const bf16x8*)(qb + ks * 64);
  }

  float m[2][4], ln[2][4];
  for (int rf = 0; rf < 2; ++rf)
    for (int rr = 0; rr < 4; ++rr) { m[rf][rr] = -1e30f; ln[rf][rr] = 0.f; }
  f32x4 o[2][8] = {};

  const uint8_t* KpB = (const uint8_t*)Kp + ((size_t)b * N_ * KVD_ + (size_t)hkv * HD_) * 2;
  const uint8_t* VtB = (const uint8_t*)Vt + (size_t)(b * HKV_ + hkv) * HD_ * (size_t)N_ * 2;

  const int T = (qtile * 32 + 31) / 64 + 1;
  for (int t = 0; t < T; ++t) {
    // S = Q K^T : kf fragments straight from global (16 rows x 64B, coalesced)
    f32x4 s4[2][4] = {};
    for (int ks = 0; ks < 4; ++ks) {
      for (int cb = 0; cb < 4; ++cb) {
        bf16x8 kf = *(const bf16x8*)(
            KpB + (size_t)(t * 64 + cb * 16 + l15) * (KVD_ * 2) + ks * 64 + lg * 16);
        s4[0][cb] = __builtin_amdgcn_mfma_f32_16x16x32_bf16(qf[0][ks], kf, s4[0][cb], 0, 0, 0);
        s4[1][cb] = __builtin_amdgcn_mfma_f32_16x16x32_bf16(qf[1][ks], kf, s4[1][cb], 0, 0, 0);
      }
    }

    // causal mask on the last tile (global row/col compare)
    if (t == T - 1) {
      for (int rf = 0; rf < 2; ++rf) {
        int grow = qtile * 32 + rf * 16 + lg * 4;
        for (int cb = 0; cb < 4; ++cb) {
          int gcol = t * 64 + cb * 16 + l15;
          for (int rr = 0; rr < 4; ++rr)
            if (gcol > grow + rr) s4[rf][cb][rr] = -1e30f;
        }
      }
    }

    // online softmax per row-frag (16-lane-group shfl reductions)
    for (int rf = 0; rf < 2; ++rf) {
      float p[4][4];
      float sc[4];
      for (int rr = 0; rr < 4; ++rr) {
        float rm = fmaxf(fmaxf(s4[rf][0][rr], s4[rf][1][rr]),
                         fmaxf(s4[rf][2][rr], s4[rf][3][rr]));
        rm = fmaxf(rm, __shfl_xor(rm, 1));
        rm = fmaxf(rm, __shfl_xor(rm, 2));
        rm = fmaxf(rm, __shfl_xor(rm, 4));
        rm = fmaxf(rm, __shfl_xor(rm, 8));
        float mn = fmaxf(m[rf][rr], rm);
        sc[rr] = __expf(m[rf][rr] - mn);
        float rs = 0.f;
        for (int cb = 0; cb < 4; ++cb) {
          p[cb][rr] = __expf(s4[rf][cb][rr] - mn);
          rs += p[cb][rr];
        }
        rs += __shfl_xor(rs, 1);
        rs += __shfl_xor(rs, 2);
        rs += __shfl_xor(rs, 4);
        rs += __shfl_xor(rs, 8);
        ln[rf][rr] = ln[rf][rr] * sc[rr] + rs;
        m[rf][rr] = mn;
      }
      f32x4 sv = {sc[0], sc[1], sc[2], sc[3]};
      for (int db = 0; db < 8; ++db) o[rf][db] *= sv;

      // P -> per-wave LDS (rows of 72 bf16)
      bf16_t* Pw = Ps[wave][rf];
      for (int cb = 0; cb < 4; ++cb)
        for (int rr = 0; rr < 4; ++rr)
          Pw[(lg * 4 + rr) * 72 + cb * 16 + l15] = (bf16_t)p[cb][rr];
    }

    // O += P @ V : vf fragments straight from global (shared by both row-frags)
    const uint8_t* P0 = (const uint8_t*)Ps[wave][0];
    const uint8_t* P1 = (const uint8_t*)Ps[wave][1];
    for (int ks2 = 0; ks2 < 2; ++ks2) {
      bf16x8 pf0 = *(const bf16x8*)(P0 + l15 * 144 + ks2 * 64 + lg * 16);
      bf16x8 pf1 = *(const bf16x8*)(P1 + l15 * 144 + ks2 * 64 + lg * 16);
      for (int db = 0; db < 8; ++db) {
        bf16x8 vf = *(const bf16x8*)(
            VtB + (size_t)(db * 16 + l15) * (N_ * 2) + t * 128 + ks2 * 64 + lg * 16);
        o[0][db] = __builtin_amdgcn_mfma_f32_16x16x32_bf16(pf0, vf, o[0][db], 0, 0, 0);
        o[1][db] = __builtin_amdgcn_mfma_f32_16x16x32_bf16(pf1, vf, o[1][db], 0, 0, 0);
      }
    }
  }

  // write AO[b*2048+n][hq*128+d]  (bf16)
  for (int rf = 0; rf < 2; ++rf) {
    size_t orow0 = (size_t)b * N_ + qtile * 32 + rf * 16 + lg * 4;
    for (int rr = 0; rr < 4; ++rr) {
      size_t off = (orow0 + rr) * DIM_ + (size_t)hq * HD_ + l15;
      float iv = 1.f / ln[rf][rr];
      for (int db = 0; db < 8; ++db)
        AO[off + db * 16] = (bf16_t)(o[rf][db][rr] * iv);
    }
  }
}

// ---------------------------------------------------------------------------
extern "C" void kernel_launch(void* const* d_in, const int* in_sizes, int n_in,
                              void* d_out, int out_size, void* d_ws, size_t ws_size,
                              hipStream_t stream)
{
  // ws layout needs 45 MB; known sufficient (round-1 signal).
  if (ws_size < (46u << 20)) return;

  const float* query = (const float*)d_in[0];
  const float* key   = (const float*)d_in[1];
  const float* value = (const float*)d_in[2];
  const float* Wq = (const float*)d_in[3];
  const float* bq = (const float*)d_in[4];
  const float* Wk = (const float*)d_in[5];
  const float* bk = (const float*)d_in[6];
  const float* Wv = (const float*)d_in[7];
  const float* bv = (const float*)d_in[8];
  const float* Wo = (const float*)d_in[9];
  const float* bo = (const float*)d_in[10];
  float* out = (float*)d_out;

  uint8_t* ws = (uint8_t*)d_ws;
  float*  cosT = (float*)(ws);                       // 512 KB
  float*  sinT = (float*)(ws + (512u << 10));        // 512 KB
  bf16_t* Qp   = (bf16_t*)(ws + (1u  << 20));        // 16 MB [4096][2048]
  bf16_t* Kp   = (bf16_t*)(ws + (17u << 20));        // 4 MB  [4096][512]
  bf16_t* Vp   = (bf16_t*)(ws + (21u << 20));        // 4 MB  [4096][512]
  bf16_t* Vt   = (bf16_t*)(ws + (25u << 20));        // 4 MB  [8][128][2048]
  bf16_t* AO   = (bf16_t*)(ws + (29u << 20));        // 16 MB [4096][2048]

  k_sincos<<<512, 256, 0, stream>>>(cosT, sinT);

  // Q projection: M=4096 N=2048 K=2048 (f32 in -> bf16 ws)
  k_gemm_bt<true, false><<<dim3(32, 16, 1), 256, 0, stream>>>(
      query, Wq, bq, Qp, query, Wq, bq, Qp, 4096, 2048, 2048);
  // K and V projections fused: M=4096 N=512 K=2048, z selects K vs V
  k_gemm_bt<true, false><<<dim3(32, 4, 2), 256, 0, stream>>>(
      key, Wk, bk, Kp, value, Wv, bv, Vp, 4096, 512, 2048);

  k_rope<<<16384, 256, 0, stream>>>(Qp, cosT, sinT, 4, SCALE_);
  k_rope<<<4096,  256, 0, stream>>>(Kp, cosT, sinT, 2, 1.0f);

  k_transpose_v<<<dim3(64, 8), 256, 0, stream>>>(Vp, Vt);

  // barrier-free flash attention: 512 blocks, 4 independent waves each
  k_attn<<<dim3(16, 32), 256, 0, stream>>>(Qp, Kp, Vt, AO);

  // Output projection: M=4096 N=2048 K=2048 (bf16 ws -> f32 out)
  k_gemm_bt<false, true><<<dim3(32, 16, 1), 256, 0, stream>>>(
      AO, Wo, bo, out, AO, Wo, bo, out, 4096, 2048, 2048);
}

// Round 5
// 352.386 us; speedup vs baseline: 1.3028x; 1.3028x over previous
//
#include <hip/hip_runtime.h>
#include <cstdint>

// ---------------------------------------------------------------------------
// GroupedQueryAttention: B=2 N=2048 DIM=2048 HQ=16 HKV=4 HD=128, causal, RoPE.
// f32 I/O, bf16 internals. Round 5: swapped-operand attention — S^T=mfma(K,Q)
// makes softmax lane-local (2 shfls instead of 64 per tile); PV swapped too so
// the normalizer never leaves the lane. Balanced wave->qtile mapping.
// ---------------------------------------------------------------------------

typedef __bf16 bf16_t;
typedef __attribute__((ext_vector_type(8))) __bf16 bf16x8;
typedef __attribute__((ext_vector_type(4))) float f32x4;

#define B_    2
#define N_    2048
#define DIM_  2048
#define HQ_   16
#define HKV_  4
#define HD_   128
#define KVD_  512
#define SCALE_ 0.08838834764831845f  // 128^-0.5

static __device__ __forceinline__ f32x4 vmax4(f32x4 a, f32x4 b) {
  f32x4 r;
  r[0] = fmaxf(a[0], b[0]); r[1] = fmaxf(a[1], b[1]);
  r[2] = fmaxf(a[2], b[2]); r[3] = fmaxf(a[3], b[3]);
  return r;
}

// ---------------------------------------------------------------------------
// cos/sin table: [2048][64] each, f32.  inv_freq = 10000^(-i/64) (base_adj==1)
// ---------------------------------------------------------------------------
__global__ void k_sincos(float* __restrict__ cosT, float* __restrict__ sinT) {
  int idx = blockIdx.x * 256 + threadIdx.x;  // 2048*64
  int i = idx & 63;
  int n = idx >> 6;
  float inv = expf(-(float)i * (9.210340371976184f / 64.0f));  // ln(1e4)/64
  float ang = (float)n * inv;
  cosT[idx] = cosf(ang);
  sinT[idx] = sinf(ang);
}

// ---------------------------------------------------------------------------
// C = A @ W^T + bias.  A:[M][K] (f32 if AF32 else bf16), W:[N][K] f32,
// C:[M][N] (f32 if CF32 else bf16).  Dual-issue via blockIdx.z.
// 128x128 tile, BK=64, 4 waves each 64x64. LDS bf16 [128][64], XOR swizzle.
// ---------------------------------------------------------------------------
template <bool AF32, bool CF32>
__global__ __launch_bounds__(256, 2) void k_gemm_bt(
    const void* __restrict__ A0v, const float* __restrict__ W0,
    const float* __restrict__ b0, void* __restrict__ C0v,
    const void* __restrict__ A1v, const float* __restrict__ W1,
    const float* __restrict__ b1, void* __restrict__ C1v,
    int M, int N, int K)
{
  const void* Av = A0v; const float* W = W0;
  const float* bias = b0; void* Cv = C0v;
  if (blockIdx.z == 1) { Av = A1v; W = W1; bias = b1; Cv = C1v; }

  __shared__ bf16_t As[128 * 64];
  __shared__ bf16_t Bs[128 * 64];
  const int tid  = threadIdx.x;
  const int lane = tid & 63;
  const int wave = tid >> 6;
  const int l15  = lane & 15;
  const int lg   = lane >> 4;
  const int bm = blockIdx.x, bn = blockIdx.y;
  const int wr = (wave >> 1) * 64, wc = (wave & 1) * 64;

  f32x4 acc[4][4] = {};

  uint8_t* AsB = (uint8_t*)As;
  uint8_t* BsB = (uint8_t*)Bs;

  for (int k0 = 0; k0 < K; k0 += 64) {
    // stage: 128 rows x 64 cols per tile = 1024 8-elem chunks, 256 thr x 4
    for (int i = 0; i < 4; ++i) {
      int c = i * 256 + tid;
      int row = c >> 3;            // 0..127
      int k8  = (c & 7) * 8;       // element offset within K-tile
      bf16x8 va, vb;
      if (AF32) {
        const float* ap = (const float*)Av + (size_t)(bm * 128 + row) * K + k0 + k8;
        f32x4 alo = *(const f32x4*)ap;
        f32x4 ahi = *(const f32x4*)(ap + 4);
        va[0] = (bf16_t)alo[0]; va[1] = (bf16_t)alo[1];
        va[2] = (bf16_t)alo[2]; va[3] = (bf16_t)alo[3];
        va[4] = (bf16_t)ahi[0]; va[5] = (bf16_t)ahi[1];
        va[6] = (bf16_t)ahi[2]; va[7] = (bf16_t)ahi[3];
      } else {
        va = *(const bf16x8*)((const bf16_t*)Av + (size_t)(bm * 128 + row) * K + k0 + k8);
      }
      {
        const float* wp = W + (size_t)(bn * 128 + row) * K + k0 + k8;
        f32x4 wlo = *(const f32x4*)wp;
        f32x4 whi = *(const f32x4*)(wp + 4);
        vb[0] = (bf16_t)wlo[0]; vb[1] = (bf16_t)wlo[1];
        vb[2] = (bf16_t)wlo[2]; vb[3] = (bf16_t)wlo[3];
        vb[4] = (bf16_t)whi[0]; vb[5] = (bf16_t)whi[1];
        vb[6] = (bf16_t)whi[2]; vb[7] = (bf16_t)whi[3];
      }
      int sw = (k8 * 2) ^ ((row & 7) << 4);
      *(bf16x8*)(AsB + row * 128 + sw) = va;
      *(bf16x8*)(BsB + row * 128 + sw) = vb;
    }
    __syncthreads();
    for (int kk = 0; kk < 2; ++kk) {
      const int koff = kk * 64 + (lg << 4);
      bf16x8 fa[4], fb[4];
      for (int fi = 0; fi < 4; ++fi) {
        int row = wr + fi * 16 + l15;
        fa[fi] = *(const bf16x8*)(AsB + row * 128 + (koff ^ ((row & 7) << 4)));
      }
      for (int fj = 0; fj < 4; ++fj) {
        int row = wc + fj * 16 + l15;
        fb[fj] = *(const bf16x8*)(BsB + row * 128 + (koff ^ ((row & 7) << 4)));
      }
      for (int fi = 0; fi < 4; ++fi)
        for (int fj = 0; fj < 4; ++fj)
          acc[fi][fj] = __builtin_amdgcn_mfma_f32_16x16x32_bf16(
              fa[fi], fb[fj], acc[fi][fj], 0, 0, 0);
    }
    __syncthreads();
  }

  // epilogue: C/D layout col=lane&15, row=(lane>>4)*4+r
  const int r0 = lg * 4;
  for (int fi = 0; fi < 4; ++fi) {
    for (int rr = 0; rr < 4; ++rr) {
      int grow = bm * 128 + wr + fi * 16 + r0 + rr;
      size_t rowoff = (size_t)grow * N;
      for (int fj = 0; fj < 4; ++fj) {
        int gcol = bn * 128 + wc + fj * 16 + l15;
        float v = acc[fi][fj][rr] + bias[gcol];
        if (CF32) ((float*)Cv)[rowoff + gcol] = v;
        else      ((bf16_t*)Cv)[rowoff + gcol] = (bf16_t)v;
      }
    }
  }
}

// ---------------------------------------------------------------------------
// RoPE in-place on X:[4096][nheads*128] bf16.  lgnh = log2(nheads). outScale
// folds the attention softmax scale into Q.
// ---------------------------------------------------------------------------
__global__ void k_rope(bf16_t* __restrict__ X, const float* __restrict__ cosT,
                       const float* __restrict__ sinT, int lgnh, float outScale)
{
  int idx = blockIdx.x * 256 + threadIdx.x;
  int d = idx & 63;
  int h = (idx >> 6) & ((1 << lgnh) - 1);
  int row = idx >> (6 + lgnh);
  int n = row & (N_ - 1);
  float c = cosT[(n << 6) + d];
  float s = sinT[(n << 6) + d];
  size_t base = (size_t)row * (size_t)(128 << lgnh) + (h << 7) + d;
  float x1 = (float)X[base];
  float x2 = (float)X[base + 64];
  X[base]      = (bf16_t)((x1 * c - x2 * s) * outScale);
  X[base + 64] = (bf16_t)((x2 * c + x1 * s) * outScale);
}

// ---------------------------------------------------------------------------
// Vp:[4096][512] -> Vt:[B*HKV][128][2048]  (Vt[bh][d][n] = Vp[b*2048+n][hkv*128+d])
// ---------------------------------------------------------------------------
__global__ void k_transpose_v(const bf16_t* __restrict__ Vp, bf16_t* __restrict__ Vt)
{
  __shared__ bf16_t tile[64][72];
  const int tid = threadIdx.x;
  const int r0 = blockIdx.x * 64;  // global row (b*2048+n)
  const int d0 = blockIdx.y * 64;  // col in [0,512)
  for (int r = 0; r < 2; ++r) {
    int n = r * 32 + (tid >> 3);
    int dc = (tid & 7) * 8;
    *(uint4*)&tile[n][dc] = *(const uint4*)(Vp + (size_t)(r0 + n) * KVD_ + d0 + dc);
  }
  __syncthreads();
  const int b = r0 >> 11;
  const int nseq = r0 & (N_ - 1);
  for (int r = 0; r < 2; ++r) {
    int dd = r * 32 + (tid >> 3);
    int nc = (tid & 7) * 8;
    int dglob = d0 + dd;
    int hkv = dglob >> 7, dloc = dglob & 127;
    union { bf16_t h[8]; uint4 v; } pk;
    for (int j = 0; j < 8; ++j) pk.h[j] = tile[nc + j][dd];
    size_t drow = (size_t)(b * HKV_ + hkv) * 128 + dloc;
    *(uint4*)(Vt + drow * N_ + nseq + nc) = pk.v;
  }
}

// ---------------------------------------------------------------------------
// Flash attention, causal GQA, barrier-free, swapped operands.
// Grid (16, B*HQ); 4 waves/block; wave owns qtile = blockIdx.x + 16*wave
// (32 queries, balanced load mix per block). S^T = mfma(K,Q) -> query = l15,
// keys in-register => softmax is in-lane + 2 shfls. PV = mfma(V,P) keeps
// query = l15 so the normalizer stays lane-local. P via per-wave LDS.
// ---------------------------------------------------------------------------
__global__ __launch_bounds__(256, 2) void k_attn(
    const bf16_t* __restrict__ Qp, const bf16_t* __restrict__ Kp,
    const bf16_t* __restrict__ Vt, bf16_t* __restrict__ AO)
{
  __shared__ bf16_t Ps[4][2][16 * 72];
  const int tid = threadIdx.x, lane = tid & 63, wave = tid >> 6;
  const int l15 = lane & 15, lg = lane >> 4;
  const int qtile = blockIdx.x + wave * 16;   // 0..63 (32 queries each)
  const int bh = blockIdx.y;
  const int b = bh >> 4, hq = bh & 15, hkv = hq >> 2;

  // Q fragments: 2 row-frags x 4 k-steps (RoPE'd, scale folded)
  bf16x8 qf[2][4];
  for (int rf = 0; rf < 2; ++rf) {
    size_t qrow = (size_t)b * N_ + qtile * 32 + rf * 16 + l15;
    const uint8_t* qb = (const uint8_t*)Qp + (qrow * DIM_ + (size_t)hq * HD_) * 2 + lg * 16;
    for (int ks = 0; ks < 4; ++ks)
      qf[rf][ks] = *(const bf16x8*)(qb + ks * 64);
  }

  float m[2] = {-1e30f, -1e30f};
  float ln[2] = {0.f, 0.f};
  f32x4 o[2][8] = {};   // o[rf][db][rr]: q = l15 (col), d = db*16+lg*4+rr (row)

  const uint8_t* KpB = (const uint8_t*)Kp + ((size_t)b * N_ * KVD_ + (size_t)hkv * HD_) * 2;
  const uint8_t* VtB = (const uint8_t*)Vt + (size_t)(b * HKV_ + hkv) * HD_ * (size_t)N_ * 2;

  const int T = (qtile * 32 + 31) / 64 + 1;
  for (int t = 0; t < T; ++t) {
    // S^T = K Q^T : s4[rf][kb], lane holds [key = kb*16+lg*4+rr][q = l15]
    f32x4 s4[2][4] = {};
    for (int ks = 0; ks < 4; ++ks) {
      for (int kb = 0; kb < 4; ++kb) {
        bf16x8 kf = *(const bf16x8*)(
            KpB + (size_t)(t * 64 + kb * 16 + l15) * (KVD_ * 2) + ks * 64 + lg * 16);
        s4[0][kb] = __builtin_amdgcn_mfma_f32_16x16x32_bf16(kf, qf[0][ks], s4[0][kb], 0, 0, 0);
        s4[1][kb] = __builtin_amdgcn_mfma_f32_16x16x32_bf16(kf, qf[1][ks], s4[1][kb], 0, 0, 0);
      }
    }

    // causal mask on the last tile: key > query -> -inf
    if (t == T - 1) {
      for (int rf = 0; rf < 2; ++rf) {
        int q = qtile * 32 + rf * 16 + l15;
        for (int kb = 0; kb < 4; ++kb) {
          int key = t * 64 + kb * 16 + lg * 4;
          for (int rr = 0; rr < 4; ++rr)
            if (key + rr > q) s4[rf][kb][rr] = -1e30f;
        }
      }
    }

    // lane-local online softmax: in-lane reduce over 16 keys + 2 shfls over lg
    for (int rf = 0; rf < 2; ++rf) {
      f32x4 mx = vmax4(vmax4(s4[rf][0], s4[rf][1]), vmax4(s4[rf][2], s4[rf][3]));
      float rm = fmaxf(fmaxf(mx[0], mx[1]), fmaxf(mx[2], mx[3]));
      rm = fmaxf(rm, __shfl_xor(rm, 16));
      rm = fmaxf(rm, __shfl_xor(rm, 32));
      float mn = fmaxf(m[rf], rm);
      float sc = __expf(m[rf] - mn);

      f32x4 p[4];
      f32x4 psum = {0.f, 0.f, 0.f, 0.f};
      for (int kb = 0; kb < 4; ++kb) {
        for (int rr = 0; rr < 4; ++rr)
          p[kb][rr] = __expf(s4[rf][kb][rr] - mn);
        psum += p[kb];
      }
      float rs = (psum[0] + psum[1]) + (psum[2] + psum[3]);
      rs += __shfl_xor(rs, 16);
      rs += __shfl_xor(rs, 32);
      ln[rf] = ln[rf] * sc + rs;
      m[rf] = mn;

      for (int db = 0; db < 8; ++db) o[rf][db] *= sc;

      // P -> per-wave LDS row q=l15: 4 packed 8B stores (keys kb*16+lg*4..+3)
      uint8_t* Pw = (uint8_t*)Ps[wave][rf];
      for (int kb = 0; kb < 4; ++kb) {
        union { bf16_t h[4]; uint2 u; } pk;
        pk.h[0] = (bf16_t)p[kb][0]; pk.h[1] = (bf16_t)p[kb][1];
        pk.h[2] = (bf16_t)p[kb][2]; pk.h[3] = (bf16_t)p[kb][3];
        *(uint2*)(Pw + l15 * 144 + kb * 32 + lg * 8) = pk.u;
      }
    }

    // O^T += V^T P^T : vf rows = d (shared by both rf), pf rows = q
    const uint8_t* P0 = (const uint8_t*)Ps[wave][0];
    const uint8_t* P1 = (const uint8_t*)Ps[wave][1];
    for (int ks2 = 0; ks2 < 2; ++ks2) {
      bf16x8 pf0 = *(const bf16x8*)(P0 + l15 * 144 + ks2 * 64 + lg * 16);
      bf16x8 pf1 = *(const bf16x8*)(P1 + l15 * 144 + ks2 * 64 + lg * 16);
      for (int db = 0; db < 8; ++db) {
        bf16x8 vf = *(const bf16x8*)(
            VtB + (size_t)(db * 16 + l15) * (N_ * 2) + t * 128 + ks2 * 64 + lg * 16);
        o[0][db] = __builtin_amdgcn_mfma_f32_16x16x32_bf16(vf, pf0, o[0][db], 0, 0, 0);
        o[1][db] = __builtin_amdgcn_mfma_f32_16x16x32_bf16(vf, pf1, o[1][db], 0, 0, 0);
      }
    }
  }

  // epilogue: lane q = l15; d = db*16 + lg*4 + rr -> packed 8B stores
  for (int rf = 0; rf < 2; ++rf) {
    float iv = 1.f / ln[rf];
    size_t qrow = (size_t)b * N_ + qtile * 32 + rf * 16 + l15;
    uint8_t* ob = (uint8_t*)(AO + qrow * DIM_ + (size_t)hq * HD_);
    for (int db = 0; db < 8; ++db) {
      union { bf16_t h[4]; uint2 u; } pk;
      pk.h[0] = (bf16_t)(o[rf][db][0] * iv);
      pk.h[1] = (bf16_t)(o[rf][db][1] * iv);
      pk.h[2] = (bf16_t)(o[rf][db][2] * iv);
      pk.h[3] = (bf16_t)(o[rf][db][3] * iv);
      *(uint2*)(ob + (db * 16 + lg * 4) * 2) = pk.u;
    }
  }
}

// ---------------------------------------------------------------------------
extern "C" void kernel_launch(void* const* d_in, const int* in_sizes, int n_in,
                              void* d_out, int out_size, void* d_ws, size_t ws_size,
                              hipStream_t stream)
{
  // ws layout needs 45 MB; known sufficient (round-1 signal).
  if (ws_size < (46u << 20)) return;

  const float* query = (const float*)d_in[0];
  const float* key   = (const float*)d_in[1];
  const float* value = (const float*)d_in[2];
  const float* Wq = (const float*)d_in[3];
  const float* bq = (const float*)d_in[4];
  const float* Wk = (const float*)d_in[5];
  const float* bk = (const float*)d_in[6];
  const float* Wv = (const float*)d_in[7];
  const float* bv = (const float*)d_in[8];
  const float* Wo = (const float*)d_in[9];
  const float* bo = (const float*)d_in[10];
  float* out = (float*)d_out;

  uint8_t* ws = (uint8_t*)d_ws;
  float*  cosT = (float*)(ws);                       // 512 KB
  float*  sinT = (float*)(ws + (512u << 10));        // 512 KB
  bf16_t* Qp   = (bf16_t*)(ws + (1u  << 20));        // 16 MB [4096][2048]
  bf16_t* Kp   = (bf16_t*)(ws + (17u << 20));        // 4 MB  [4096][512]
  bf16_t* Vp   = (bf16_t*)(ws + (21u << 20));        // 4 MB  [4096][512]
  bf16_t* Vt   = (bf16_t*)(ws + (25u << 20));        // 4 MB  [8][128][2048]
  bf16_t* AO   = (bf16_t*)(ws + (29u << 20));        // 16 MB [4096][2048]

  k_sincos<<<512, 256, 0, stream>>>(cosT, sinT);

  // Q projection: M=4096 N=2048 K=2048 (f32 in -> bf16 ws)
  k_gemm_bt<true, false><<<dim3(32, 16, 1), 256, 0, stream>>>(
      query, Wq, bq, Qp, query, Wq, bq, Qp, 4096, 2048, 2048);
  // K and V projections fused: M=4096 N=512 K=2048, z selects K vs V
  k_gemm_bt<true, false><<<dim3(32, 4, 2), 256, 0, stream>>>(
      key, Wk, bk, Kp, value, Wv, bv, Vp, 4096, 512, 2048);

  k_rope<<<16384, 256, 0, stream>>>(Qp, cosT, sinT, 4, SCALE_);
  k_rope<<<4096,  256, 0, stream>>>(Kp, cosT, sinT, 2, 1.0f);

  k_transpose_v<<<dim3(64, 8), 256, 0, stream>>>(Vp, Vt);

  // barrier-free swapped-operand flash attention
  k_attn<<<dim3(16, 32), 256, 0, stream>>>(Qp, Kp, Vt, AO);

  // Output projection: M=4096 N=2048 K=2048 (bf16 ws -> f32 out)
  k_gemm_bt<false, true><<<dim3(32, 16, 1), 256, 0, stream>>>(
      AO, Wo, bo, out, AO, Wo, bo, out, 4096, 2048, 2048);
}